// Round 10
// baseline (1938.605 us; speedup 1.0000x reference)
//
#include <hip/hip_runtime.h>
#include <math.h>

#define BB 4
#define CIN 256
#define CH 128
#define KDIM 32
#define HIN 32
#define HY 65
#define NPIX 4225  // 65*65

// ---------- diagnostic sentinel ----------
__global__ void sentinel_kernel(float* __restrict__ out, int n, float val) {
  int i = blockIdx.x * 256 + threadIdx.x;
  if (i < n) out[i] = val;
}

// ---------- transpose ConvTranspose weights -> Wtr[kh*3+kw][ci][co] ----------
// JAX conv_transpose('IOHW', transpose_kernel=True): contraction runs over the
// 'O'-labeled axis (Wt axis 1), output over the 'I'-labeled axis (Wt axis 0);
// spatial flip cancels against lhs_dilation giving oh = 2*ih + kh.
//   h[b,co] = sum_ci x[b,ci] * Wt[co, ci, kh, kw]
__global__ void wtr_kernel(const float* __restrict__ wt, float* __restrict__ wtr) {
  int idx = blockIdx.x * 256 + threadIdx.x;
  if (idx >= 9 * CIN * CIN) return;
  int co = idx & 255;
  int ci = (idx >> 8) & 255;
  int kk = idx >> 16;
  wtr[idx] = wt[(co * CIN + ci) * 9 + kk];   // contraction over Wt axis 1
}

// ---------- ConvTranspose2d(k=3,s=2,p=0) + bias + ReLU ----------
__global__ __launch_bounds__(256) void ct_kernel(const float* __restrict__ x,
    const float* __restrict__ wtr, const float* __restrict__ bt, float* __restrict__ out) {
  const int co  = threadIdx.x;
  const int ow0 = blockIdx.x * 16;
  const int oh  = blockIdx.y;
  const int b   = blockIdx.z;

  int khs[2] = {0, 0}, ihs[2] = {0, 0};
  int nkh = 0;
  #pragma unroll
  for (int kh = 0; kh < 3; kh++) {
    if (((oh - kh) & 1) == 0) {
      int ih = (oh - kh) >> 1;
      if (ih >= 0 && ih < HIN) { khs[nkh] = kh; ihs[nkh] = ih; nkh++; }
    }
  }
  const int iwb = (ow0 >> 1) - 1;

  float acc[16];
  #pragma unroll
  for (int i = 0; i < 16; i++) acc[i] = 0.f;

  for (int ci = 0; ci < CIN; ci++) {
    float xv[2][9];
    #pragma unroll
    for (int j = 0; j < 2; j++) {
      #pragma unroll
      for (int t = 0; t < 9; t++) {
        int iw = iwb + t;
        xv[j][t] = (j < nkh && iw >= 0 && iw < HIN)
                 ? x[((b * CIN + ci) * HIN + ihs[j]) * HIN + iw] : 0.f;
      }
    }
    #pragma unroll
    for (int j = 0; j < 2; j++) {
      if (j >= nkh) continue;
      #pragma unroll
      for (int kw = 0; kw < 3; kw++) {
        float wv = wtr[((khs[j] * 3 + kw) * CIN + ci) * CIN + co];
        #pragma unroll
        for (int owi = 0; owi < 16; owi++) {
          if ((owi & 1) == (kw & 1)) {
            const int t = ((owi - kw) >> 1) + 1;  // compile-time; OOB iw already zeroed
            acc[owi] = fmaf(wv, xv[j][t], acc[owi]);
          }
        }
      }
    }
  }
  const float bias = bt[co];
  #pragma unroll
  for (int owi = 0; owi < 16; owi++) {
    int ow = ow0 + owi;
    if (ow < HY) {
      float v = acc[owi] + bias;
      out[((b * CIN + co) * HY + oh) * HY + ow] = v > 0.f ? v : 0.f;
    }
  }
}

// ---------- generic 3x3 conv, stride1, pad1. MODE 0: raw out; MODE 1: +bias +ReLU ----------
template<int MODE>
__global__ __launch_bounds__(192) void conv3x3_k(const float* __restrict__ in,
    const float* __restrict__ w, const float* __restrict__ bias,
    float* __restrict__ out, int Ci, int Co) {
  __shared__ float patch[15 * 17];
  const int t    = threadIdx.x;
  const int tile = blockIdx.x;
  const int ty0  = (tile / 5) * 13, tx0 = (tile % 5) * 13;
  const int co0  = blockIdx.y * 8;
  const int b    = blockIdx.z;
  const int ty   = t / 13, tx = t - ty * 13;
  const bool act = t < 169;

  float acc[8];
  #pragma unroll
  for (int u = 0; u < 8; u++) acc[u] = 0.f;

  for (int ci = 0; ci < Ci; ci++) {
    __syncthreads();
    const float* inp = in + (size_t)(b * Ci + ci) * NPIX;
    for (int e = t; e < 225; e += 192) {
      int r = e / 15, c = e - r * 15;
      int gy = ty0 - 1 + r, gx = tx0 - 1 + c;
      patch[r * 17 + c] = (gy >= 0 && gy < HY && gx >= 0 && gx < HY) ? inp[gy * HY + gx] : 0.f;
    }
    __syncthreads();
    if (act) {
      float p[9];
      #pragma unroll
      for (int kh = 0; kh < 3; kh++)
        #pragma unroll
        for (int kw = 0; kw < 3; kw++)
          p[kh * 3 + kw] = patch[(ty + kh) * 17 + tx + kw];
      const float* wp = w + ((size_t)co0 * Ci + ci) * 9;   // uniform -> s_load
      #pragma unroll
      for (int u = 0; u < 8; u++) {
        const float* wu = wp + (size_t)u * Ci * 9;
        float s = acc[u];
        #pragma unroll
        for (int k = 0; k < 9; k++) s = fmaf(p[k], wu[k], s);
        acc[u] = s;
      }
    }
  }
  if (act) {
    const int yy = ty0 + ty, xx = tx0 + tx;
    #pragma unroll
    for (int u = 0; u < 8; u++) {
      float v = acc[u];
      if (MODE == 1) { v += bias[co0 + u]; v = v > 0.f ? v : 0.f; }
      out[(size_t)(b * Co + co0 + u) * NPIX + yy * HY + xx] = v;
    }
  }
}

// ---------- training-mode BN: per-channel mean/var over (B,H,W) -> scale/shift ----------
__global__ __launch_bounds__(256) void bn_stats_k(const float* __restrict__ t,
    const float* __restrict__ g, const float* __restrict__ bb,
    float* __restrict__ scale, float* __restrict__ shift) {
  const int c = blockIdx.x;
  const int tid = threadIdx.x;
  float s = 0.f, s2 = 0.f;
  for (int b = 0; b < BB; b++) {
    const float* p = t + (size_t)(b * CH + c) * NPIX;
    for (int i = tid; i < NPIX; i += 256) { float v = p[i]; s += v; s2 = fmaf(v, v, s2); }
  }
  __shared__ float ls[256], ls2[256];
  ls[tid] = s; ls2[tid] = s2;
  __syncthreads();
  for (int o = 128; o > 0; o >>= 1) {
    if (tid < o) { ls[tid] += ls[tid + o]; ls2[tid] += ls2[tid + o]; }
    __syncthreads();
  }
  if (tid == 0) {
    const float N = (float)(BB * NPIX);
    float m   = ls[0] / N;
    float var = ls2[0] / N - m * m;
    float sc  = g[c] * rsqrtf(var + 1e-5f);
    scale[c] = sc;
    shift[c] = bb[c] - m * sc;
  }
}

// in-place BN apply + ReLU
__global__ __launch_bounds__(256) void bn_apply_k(float* __restrict__ buf,
    const float* __restrict__ scale, const float* __restrict__ shift) {
  const int bc = blockIdx.x;
  const int c  = bc & (CH - 1);
  const float sc = scale[c], sh = shift[c];
  float* p = buf + (size_t)bc * NPIX;
  for (int i = threadIdx.x; i < NPIX; i += 256) {
    float v = fmaf(p[i], sc, sh);
    p[i] = v > 0.f ? v : 0.f;
  }
}

// ---------- depthwise 3x3 (groups=C) + bias + ReLU ----------
__global__ __launch_bounds__(256) void dwq_kernel(const float* __restrict__ y,
    const float* __restrict__ wq, const float* __restrict__ bq, float* __restrict__ qout) {
  const int bc = blockIdx.x;
  const int c  = bc & (CH - 1);
  float wv[9];
  #pragma unroll
  for (int k = 0; k < 9; k++) wv[k] = wq[c * 9 + k];
  const float bqv = bq[c];
  const float* yp = y + (size_t)bc * NPIX;
  float* qp = qout + (size_t)bc * NPIX;
  for (int i = threadIdx.x; i < NPIX; i += 256) {
    int yy = i / HY, xx = i - yy * HY;
    float s = bqv;
    #pragma unroll
    for (int kh = 0; kh < 3; kh++) {
      int gy = yy + kh - 1;
      if (gy < 0 || gy >= HY) continue;
      #pragma unroll
      for (int kw = 0; kw < 3; kw++) {
        int gx = xx + kw - 1;
        if (gx < 0 || gx >= HY) continue;
        s = fmaf(yp[gy * HY + gx], wv[kh * 3 + kw], s);
      }
    }
    qp[i] = s > 0.f ? s : 0.f;
  }
}

// ---------- gate: softmax over KD of q*k, dot with v=relu(y*Wv+bv) ----------
__global__ __launch_bounds__(256) void gate_kernel(const float* __restrict__ q,
    const float* __restrict__ k4, const float* __restrict__ y,
    const float* __restrict__ wv, const float* __restrict__ bv, float* __restrict__ g) {
  const int idx = blockIdx.x * 256 + threadIdx.x;
  if (idx >= BB * CH * NPIX) return;
  const int pix = idx % NPIX;
  const int bc  = idx / NPIX;
  const int b   = bc / CH;
  const float qv = q[idx], yv = y[idx];
  const float* kp = k4 + (size_t)b * KDIM * NPIX + pix;
  float s[KDIM];
  float mx = -1e30f;
  #pragma unroll
  for (int kd = 0; kd < KDIM; kd++) {
    s[kd] = qv * kp[(size_t)kd * NPIX];
    mx = fmaxf(mx, s[kd]);
  }
  float se = 0.f, acc = 0.f;
  #pragma unroll
  for (int kd = 0; kd < KDIM; kd++) {
    float e = __expf(s[kd] - mx);
    se += e;
    float vvv = fmaf(yv, wv[kd], bv[kd]);
    vvv = vvv > 0.f ? vvv : 0.f;
    acc = fmaf(e, vvv, acc);
  }
  g[idx] = acc / se;
}

extern "C" void kernel_launch(void* const* d_in, const int* in_sizes, int n_in,
                              void* d_out, int out_size, void* d_ws, size_t ws_size,
                              hipStream_t stream) {
  float* out = (float*)d_out;
  float* ws  = (float*)d_ws;
  const int sgrid = (out_size + 255) / 256;

  // ---- diagnostic guards (deterministic; all passed in R7) ----
  static const int EXP_SIZES[22] = {
    1048576, 2163200, 589824, 256, 294912, 128, 128, 147456, 128, 128,
    1152, 128, 36864, 32, 32, 32, 147456, 128, 128, 147456, 128, 128
  };
  if (n_in != 22) { sentinel_kernel<<<sgrid, 256, 0, stream>>>(out, out_size, 4000.0f); return; }
  for (int i = 0; i < 22; i++) {
    if (in_sizes[i] != EXP_SIZES[i]) {
      sentinel_kernel<<<sgrid, 256, 0, stream>>>(out, out_size, 2000.0f + i);
      return;
    }
  }
  if (out_size != 2163200) { sentinel_kernel<<<sgrid, 256, 0, stream>>>(out, out_size, 3000.0f); return; }
  const size_t NEEDED = (size_t)9783680 * 4;  // 39.13 MB
  if (ws_size < NEEDED) { sentinel_kernel<<<sgrid, 256, 0, stream>>>(out, out_size, 1000.0f); return; }

  const float* x  = (const float*)d_in[0];
  const float* y  = (const float*)d_in[1];
  const float* Wt = (const float*)d_in[2];
  const float* bt = (const float*)d_in[3];
  const float* W1 = (const float*)d_in[4];
  const float* g1 = (const float*)d_in[5];
  const float* b1 = (const float*)d_in[6];
  const float* W2 = (const float*)d_in[7];
  const float* g2 = (const float*)d_in[8];
  const float* b2 = (const float*)d_in[9];
  const float* Wq = (const float*)d_in[10];
  const float* bq = (const float*)d_in[11];
  const float* Wk = (const float*)d_in[12];
  const float* bk = (const float*)d_in[13];
  const float* Wv = (const float*)d_in[14];
  const float* bv = (const float*)d_in[15];
  const float* W3 = (const float*)d_in[16];
  const float* g3 = (const float*)d_in[17];
  const float* b3 = (const float*)d_in[18];
  const float* W4 = (const float*)d_in[19];
  const float* g4 = (const float*)d_in[20];
  const float* b4 = (const float*)d_in[21];

  // workspace layout (floats) — no aliasing beyond proven-safe Hb reuse. 9,783,680 fl.
  float* WTR = ws;                  // 589824
  float* Hb  = WTR + 589824;        // 4326400  (4,256,65,65)
  float* T1  = Hb + 4326400;        // 2163200
  float* T2  = T1 + 2163200;        // 2163200
  float* K4  = T2 + 2163200;        // 540800   (4,32,65,65)
  float* SC  = K4 + 540800;         // 128
  float* SH  = SC + 128;            // 128
  float* Qb  = Hb;                  // alias: Hb dead after conv1
  float* Gb  = Hb + 2163200;        // alias: second half of Hb region

  // --- weight prep ---
  wtr_kernel<<<2304, 256, 0, stream>>>(Wt, WTR);

  // --- up path ---
  ct_kernel<<<dim3(5, 65, 4), 256, 0, stream>>>(x, WTR, bt, Hb);
  conv3x3_k<0><<<dim3(25, 16, 4), 192, 0, stream>>>(Hb, W1, nullptr, T1, 256, 128);
  bn_stats_k<<<128, 256, 0, stream>>>(T1, g1, b1, SC, SH);
  bn_apply_k<<<512, 256, 0, stream>>>(T1, SC, SH);
  conv3x3_k<0><<<dim3(25, 16, 4), 192, 0, stream>>>(T1, W2, nullptr, T2, 128, 128);
  bn_stats_k<<<128, 256, 0, stream>>>(T2, g2, b2, SC, SH);
  bn_apply_k<<<512, 256, 0, stream>>>(T2, SC, SH);   // T2 = xu

  // --- gate ---
  dwq_kernel<<<512, 256, 0, stream>>>(y, Wq, bq, Qb);
  conv3x3_k<1><<<dim3(25, 4, 4), 192, 0, stream>>>(T2, Wk, bk, K4, 128, 32);
  gate_kernel<<<8450, 256, 0, stream>>>(Qb, K4, y, Wv, bv, Gb);

  // --- final DoubleConv ---
  conv3x3_k<0><<<dim3(25, 16, 4), 192, 0, stream>>>(Gb, W3, nullptr, T1, 128, 128);
  bn_stats_k<<<128, 256, 0, stream>>>(T1, g3, b3, SC, SH);
  bn_apply_k<<<512, 256, 0, stream>>>(T1, SC, SH);
  conv3x3_k<0><<<dim3(25, 16, 4), 192, 0, stream>>>(T1, W4, nullptr, out, 128, 128);
  bn_stats_k<<<128, 256, 0, stream>>>(out, g4, b4, SC, SH);
  bn_apply_k<<<512, 256, 0, stream>>>(out, SC, SH);
}